// Round 1
// baseline (1350.364 us; speedup 1.0000x reference)
//
#include <hip/hip_runtime.h>

#define T_TOK 65536
#define HDIM  1024
#define NSEG  64

typedef _Float16 half8  __attribute__((ext_vector_type(8)));
typedef float    f32x4  __attribute__((ext_vector_type(4)));
typedef float    f32x16 __attribute__((ext_vector_type(16)));

typedef __attribute__((address_space(1))) const void gvoid;
typedef __attribute__((address_space(3))) void lvoid;

// ---- workspace layout (bytes) ----
#define WT_OFF     0ull                       // _Float16 image: 128 tiles x 16KB = 2MB
#define U0_OFF     2097152ull                 // float[1024]: gamma*Wout[:,0]
#define U1_OFF     (U0_OFF + 4096ull)         // float[1024]: gamma*Wout[:,1]
#define CON_OFF    (U1_OFF + 4096ull)         // float[4]: G0,G1,Bt0,Bt1
#define ACC_OFF    (CON_OFF + 64ull)          // float[64*2] segment logit sums
#define STARTS_OFF (ACC_OFF + 512ull)         // int[65] segment starts
#define ROWRED_OFF (STARTS_OFF + 512ull)      // float[65536][4]: s1,s2,p0,p1 (1MB)

// ---------------------------------------------------------------------------
// k0: u-vectors + scalar consts + zero segacc.  (tiny, 1 block)
// ---------------------------------------------------------------------------
__global__ void prep_kernel(const float* __restrict__ gamma, const float* __restrict__ beta,
                            const float* __restrict__ wout,
                            float* __restrict__ u0, float* __restrict__ u1,
                            float* __restrict__ consts, float* __restrict__ segacc) {
    __shared__ float cacc[4];
    int tid = threadIdx.x;                       // blockDim = 1024 = HDIM
    if (tid < 128) segacc[tid] = 0.f;
    if (tid < 4)   cacc[tid]   = 0.f;
    __syncthreads();

    float g  = gamma[tid], be = beta[tid];
    float w0 = wout[2 * tid], w1 = wout[2 * tid + 1];
    float a0 = g * w0, a1 = g * w1;
    u0[tid] = a0; u1[tid] = a1;
    float v[4] = {a0, a1, be * w0, be * w1};
#pragma unroll
    for (int q = 0; q < 4; ++q) {
        float x = v[q];
#pragma unroll
        for (int off = 32; off > 0; off >>= 1) x += __shfl_down(x, off, 64);
        if ((tid & 63) == 0) atomicAdd(&cacc[q], x);
    }
    __syncthreads();
    if (tid < 4) consts[tid] = cacc[tid];
}

// ---------------------------------------------------------------------------
// k1: parallel segment-boundary scan (sorted ids) + zero rowred.
//     64 blocks x 1024 threads: one thread per token.
// ---------------------------------------------------------------------------
__global__ void bounds_kernel(const int* __restrict__ segids, int* __restrict__ starts,
                              float* __restrict__ rowred) {
    int gid = blockIdx.x * 1024 + threadIdx.x;   // 0..65535
    ((f32x4*)rowred)[gid] = (f32x4){0.f, 0.f, 0.f, 0.f};
    if (gid == 0) { starts[0] = 0; starts[NSEG] = T_TOK; }
    if (gid < T_TOK - 1) {
        int s0 = segids[gid], s1 = segids[gid + 1];
        if (s1 != s0) starts[s1] = gid + 1;
    }
}

// ---------------------------------------------------------------------------
// k2: arrange W [k][col] fp32 -> fp16 tile image, fragment-chunk order.
// Image: [cb 8][kq 16] tiles of 16KB; tile chunk c = kh*128+col holds
// 8 halves W[kq*64+kh*8+j][cb*128+col].  Linear LDS copy + conflict-free reads.
// Grid: 128 blocks (cb*16+kq) x 256 threads.
// ---------------------------------------------------------------------------
__global__ void wconv_kernel(const float* __restrict__ W, _Float16* __restrict__ Wt) {
    int b  = blockIdx.x;
    int cb = b >> 4, kq = b & 15;
    int t  = threadIdx.x;
    half8* outp = (half8*)Wt + (size_t)b * 1024;
#pragma unroll
    for (int i = 0; i < 4; ++i) {
        int c = t + i * 256;
        int col = c & 127, kh = c >> 7;
        const float* src = W + (size_t)(kq * 64 + kh * 8) * HDIM + cb * 128 + col;
        half8 v;
#pragma unroll
        for (int j = 0; j < 8; ++j) v[j] = (_Float16)src[(size_t)j * HDIM];
        outp[c] = v;   // coalesced 16B stores; reads coalesced per j
    }
}

// ---------------------------------------------------------------------------
// k3: GEMM + residual + per-row partial reductions (s1,s2,p0,p1) -> rowred.
// m97 structure: 128x128 tile, BK=64, 256 threads (4 waves 2x2, each 64x64
// as 2x2 mfma_32x32x16_f16).  B tile via global_load_lds from arranged image
// (linear dest, conflict-free fragment reads).  A reg-staged fp32->fp16 into
// fragment-chunk LDS.  Col-siblings of a row panel mapped to one XCD.
// ---------------------------------------------------------------------------
__global__ __launch_bounds__(256, 3) void gemm_kernel(
    const float* __restrict__ A, const float* __restrict__ R,
    const float* __restrict__ bdense, const _Float16* __restrict__ Wt,
    const float* __restrict__ u0g, const float* __restrict__ u1g,
    float* __restrict__ rowred) {
    __shared__ __align__(16) char smem[32768];   // A:[0,16K) B:[16K,32K); epi reuses A
    int tid  = threadIdx.x;
    int lane = tid & 63, wave = tid >> 6;
    int ln = lane & 31, lh = lane >> 5;
    int wrow = wave >> 1, wcol = wave & 1;

    // XCD-local col-sibling mapping: XCD x owns row panels == x (mod 8),
    // iterating its 8 col blocks fastest -> A panel stays in that XCD's L2.
    int bid  = blockIdx.x;
    int xcd  = bid & 7, seq = bid >> 3;
    int vcol = seq & 7;
    int vrow = (seq >> 3) * 8 + xcd;
    int rowBase = vrow * 128, colBase = vcol * 128;

    f32x16 acc[2][2];
#pragma unroll
    for (int tr = 0; tr < 2; ++tr)
#pragma unroll
        for (int tc = 0; tc < 2; ++tc)
#pragma unroll
            for (int i = 0; i < 16; ++i) acc[tr][tc][i] = 0.f;

    // staging roles: thread t -> row t>>1, k-half t&1 (32 floats contiguous)
    int srow = tid >> 1, shalf = tid & 1;
    const float* asrc0 = A + (size_t)(rowBase + srow) * HDIM + shalf * 32;
    char* aLds = smem;
    char* bLds = smem + 16384;
    char* aWr  = aLds + (size_t)(shalf * 4 * 128 + srow) * 16;   // + j*2048
    const char* bsrc0 = (const char*)Wt + (size_t)(vcol * 16) * 16384 + wave * 4096 + lane * 16;
    char* bdst = bLds + wave * 4096;   // wave-uniform dest

    for (int kq = 0; kq < 16; ++kq) {
        __syncthreads();                         // previous tile fully consumed
        // ---- B tile: 16KB linear, 4 x global_load_lds(16B) per wave ----
        const char* bs = bsrc0 + (size_t)kq * 16384;
#pragma unroll
        for (int i = 0; i < 4; ++i)
            __builtin_amdgcn_global_load_lds((gvoid*)(bs + i * 1024),
                                             (lvoid*)(bdst + i * 1024), 16, 0, 0);
        // ---- A tile: 8 x f32x4 loads -> fp16 -> 4 x ds_write_b128 ----
        const float* as = asrc0 + kq * 64;
        f32x4 a[8];
#pragma unroll
        for (int i = 0; i < 8; ++i) a[i] = *(const f32x4*)(as + i * 4);
#pragma unroll
        for (int j = 0; j < 4; ++j) {
            f32x4 lo = a[2 * j], hi = a[2 * j + 1];
            half8 s;
            s[0] = (_Float16)lo[0]; s[1] = (_Float16)lo[1];
            s[2] = (_Float16)lo[2]; s[3] = (_Float16)lo[3];
            s[4] = (_Float16)hi[0]; s[5] = (_Float16)hi[1];
            s[6] = (_Float16)hi[2]; s[7] = (_Float16)hi[3];
            *(half8*)(aWr + j * 2048) = s;
        }
        __syncthreads();                         // stage visible (vmcnt0+lgkm0)
        // ---- compute: 4 K-steps of K=16, 2x2 MFMA each ----
#pragma unroll
        for (int ks = 0; ks < 4; ++ks) {
            int kh = ks * 2 + lh;
            half8 afr[2], bfr[2];
#pragma unroll
            for (int tr = 0; tr < 2; ++tr)
                afr[tr] = *(const half8*)(aLds + (size_t)(kh * 128 + wrow * 64 + tr * 32 + ln) * 16);
#pragma unroll
            for (int tc = 0; tc < 2; ++tc)
                bfr[tc] = *(const half8*)(bLds + (size_t)(kh * 128 + wcol * 64 + tc * 32 + ln) * 16);
#pragma unroll
            for (int tr = 0; tr < 2; ++tr)
#pragma unroll
                for (int tc = 0; tc < 2; ++tc)
                    acc[tr][tc] = __builtin_amdgcn_mfma_f32_32x32x16_f16(
                        afr[tr], bfr[tc], acc[tr][tc], 0, 0, 0);
        }
    }

    // ---- epilogue: h = acc + b + r ; partial s1,s2,p0,p1 per row ----
    __syncthreads();
    float* red = (float*)smem;                   // [4 q][128 rows][8 slots] = 16KB
#pragma unroll
    for (int i = 0; i < 16; ++i) red[tid + i * 256] = 0.f;
    __syncthreads();

    float bv[2], u0v[2], u1v[2];
#pragma unroll
    for (int tc = 0; tc < 2; ++tc) {
        int c = colBase + wcol * 64 + tc * 32 + ln;
        bv[tc] = bdense[c]; u0v[tc] = u0g[c]; u1v[tc] = u1g[c];
    }
    int slot = ln & 7;
#pragma unroll
    for (int tr = 0; tr < 2; ++tr)
#pragma unroll
        for (int reg = 0; reg < 16; ++reg) {
            int rIT  = (reg & 3) + 8 * (reg >> 2) + 4 * lh;   // C/D row map (m74/m101)
            int rloc = wrow * 64 + tr * 32 + rIT;
            size_t grow = (size_t)(rowBase + rloc);
            const float* rp = R + grow * HDIM + colBase + wcol * 64 + ln;
            float h0 = acc[tr][0][reg] + bv[0] + rp[0];
            float h1 = acc[tr][1][reg] + bv[1] + rp[32];
            atomicAdd(&red[(0 * 128 + rloc) * 8 + slot], h0 + h1);
            atomicAdd(&red[(1 * 128 + rloc) * 8 + slot], h0 * h0 + h1 * h1);
            atomicAdd(&red[(2 * 128 + rloc) * 8 + slot], h0 * u0v[0] + h1 * u0v[1]);
            atomicAdd(&red[(3 * 128 + rloc) * 8 + slot], h0 * u1v[0] + h1 * u1v[1]);
        }
    __syncthreads();
    for (int s = tid; s < 512; s += 256) {       // (q,row) pairs
        int q = s >> 7, row = s & 127;
        const float* rr = &red[(q * 128 + row) * 8];
        float v = rr[0] + rr[1] + rr[2] + rr[3] + rr[4] + rr[5] + rr[6] + rr[7];
        atomicAdd(&rowred[(size_t)(rowBase + row) * 4 + q], v);
    }
}

// ---------------------------------------------------------------------------
// k4: per-row LN finalize + segment-run combine.  256 blocks x 256 threads.
// ---------------------------------------------------------------------------
__global__ void rowfinal_kernel(const float* __restrict__ rowred, const int* __restrict__ segids,
                                const float* __restrict__ consts, float* __restrict__ segacc) {
    __shared__ float sval[256][2];
    __shared__ int   sseg[256];
    int t   = threadIdx.x;
    int row = blockIdx.x * 256 + t;
    f32x4 v = ((const f32x4*)rowred)[row];       // s1,s2,p0,p1
    float mu  = v[0] * (1.f / 1024.f);
    float var = v[1] * (1.f / 1024.f) - mu * mu;
    float rsd = rsqrtf(var + 1e-12f);
    sval[t][0] = rsd * (v[2] - mu * consts[0]) + consts[2];
    sval[t][1] = rsd * (v[3] - mu * consts[1]) + consts[3];
    sseg[t] = segids[row];
    __syncthreads();
    int s = sseg[t];
    if (t == 255 || sseg[t + 1] != s) {          // run end -> one atomic pair per run
        float a0 = 0.f, a1 = 0.f;
        int rr = t;
        while (rr >= 0 && sseg[rr] == s) { a0 += sval[rr][0]; a1 += sval[rr][1]; --rr; }
        atomicAdd(&segacc[s * 2],     a0);
        atomicAdd(&segacc[s * 2 + 1], a1);
    }
}

// ---------------------------------------------------------------------------
// k5: logits[b][l] = segacc[b][l] / count[b] + b_out[l]
// ---------------------------------------------------------------------------
__global__ void finalize_kernel(const float* __restrict__ segacc, const int* __restrict__ starts,
                                const float* __restrict__ bout, float* __restrict__ out) {
    int t = threadIdx.x;
    if (t < 128) {
        int s = t >> 1, l = t & 1;
        int cnt = starts[s + 1] - starts[s];
        out[t] = segacc[t] / (float)cnt + bout[l];
    }
}

extern "C" void kernel_launch(void* const* d_in, const int* in_sizes, int n_in,
                              void* d_out, int out_size, void* d_ws, size_t ws_size,
                              hipStream_t stream) {
    const float* A      = (const float*)d_in[0];  // sequence_attention_embeddings [T,H]
    const float* R      = (const float*)d_in[1];  // sequence_embeddings [T,H]
    const float* Wd     = (const float*)d_in[2];  // W_dense [H,H]
    const float* bdense = (const float*)d_in[3];  // b_dense [H]
    const float* gamma  = (const float*)d_in[4];  // gamma [H]
    const float* beta   = (const float*)d_in[5];  // beta [H]
    const float* wout   = (const float*)d_in[6];  // W_out [H,2]
    const float* bout   = (const float*)d_in[7];  // b_out [2]
    const int*   segids = (const int*)d_in[8];    // segment_ids [T]
    float* out = (float*)d_out;

    char* ws = (char*)d_ws;
    _Float16* Wt  = (_Float16*)(ws + WT_OFF);
    float* u0     = (float*)(ws + U0_OFF);
    float* u1     = (float*)(ws + U1_OFF);
    float* consts = (float*)(ws + CON_OFF);
    float* segacc = (float*)(ws + ACC_OFF);
    int*   starts = (int*)(ws + STARTS_OFF);
    float* rowred = (float*)(ws + ROWRED_OFF);

    prep_kernel<<<1, 1024, 0, stream>>>(gamma, beta, wout, u0, u1, consts, segacc);
    bounds_kernel<<<64, 1024, 0, stream>>>(segids, starts, rowred);
    wconv_kernel<<<128, 256, 0, stream>>>(Wd, Wt);
    gemm_kernel<<<4096, 256, 0, stream>>>(A, R, bdense, Wt, u0, u1, rowred);
    rowfinal_kernel<<<256, 256, 0, stream>>>(rowred, segids, consts, segacc);
    finalize_kernel<<<1, 128, 0, stream>>>(segacc, starts, bout, out);
}

// Round 2
// 1315.641 us; speedup vs baseline: 1.0264x; 1.0264x over previous
//
#include <hip/hip_runtime.h>

#define T_TOK 65536
#define HDIM  1024
#define NSEG  64

typedef _Float16 half8  __attribute__((ext_vector_type(8)));
typedef _Float16 half4  __attribute__((ext_vector_type(4)));
typedef float    f32x4  __attribute__((ext_vector_type(4)));
typedef float    f32x16 __attribute__((ext_vector_type(16)));

typedef __attribute__((address_space(1))) const void gvoid;
typedef __attribute__((address_space(3))) void lvoid;

// ---- workspace layout (bytes) ----
#define WT_OFF     0ull                       // _Float16 image: 128 tiles x 16KB = 2MB
#define U0_OFF     2097152ull                 // float[1024]: gamma*Wout[:,0]
#define U1_OFF     (U0_OFF + 4096ull)         // float[1024]: gamma*Wout[:,1]
#define CON_OFF    (U1_OFF + 4096ull)         // float[4]: G0,G1,Bt0,Bt1
#define ACC_OFF    (CON_OFF + 64ull)          // float[64*2] segment logit sums
#define STARTS_OFF (ACC_OFF + 512ull)         // int[65] segment starts
#define ROWRED_OFF (STARTS_OFF + 512ull)      // float[65536][4]: s1,s2,p0,p1 (1MB)
#define A16_OFF    4194304ull                 // fp16 A image: 512 rb x 16 kq x 16KB = 128MB
#define A16_BYTES  134217728ull
#define WS_NEED    (A16_OFF + A16_BYTES)

// ---------------------------------------------------------------------------
// setup: one launch, role by blockIdx.
//   [0,128)    wconv: W [k][col] fp32 -> fp16 tile image (fragment-chunk order)
//   [128,384)  bounds: segment boundary scan + zero rowred
//   384        prep: u-vectors, consts, zero segacc
//   [385,897)  aconv (fast path only): A fp32 -> fp16 tile image, same order
// ---------------------------------------------------------------------------
__global__ void setup_kernel(const float* __restrict__ A, const float* __restrict__ W,
                             const float* __restrict__ gamma, const float* __restrict__ beta,
                             const float* __restrict__ wout, const int* __restrict__ segids,
                             _Float16* __restrict__ Wt, _Float16* __restrict__ A16,
                             float* __restrict__ u0, float* __restrict__ u1,
                             float* __restrict__ consts, float* __restrict__ segacc,
                             int* __restrict__ starts, float* __restrict__ rowred) {
    int bid = blockIdx.x;
    int t   = threadIdx.x;                      // 256 threads

    if (bid < 128) {
        // ---- wconv: tile b = [cb 8][kq 16]; chunk c = kh*128+col holds
        // 8 halves W[kq*64+kh*8+j][cb*128+col] ----
        int cb = bid >> 4, kq = bid & 15;
        half8* outp = (half8*)Wt + (size_t)bid * 1024;
#pragma unroll
        for (int i = 0; i < 4; ++i) {
            int c = t + i * 256;
            int col = c & 127, kh = c >> 7;
            const float* src = W + (size_t)(kq * 64 + kh * 8) * HDIM + cb * 128 + col;
            half8 v;
#pragma unroll
            for (int j = 0; j < 8; ++j) v[j] = (_Float16)src[(size_t)j * HDIM];
            outp[c] = v;
        }
    } else if (bid < 384) {
        // ---- bounds + rowred zero ----
        int gid = (bid - 128) * 256 + t;        // 0..65535
        ((f32x4*)rowred)[gid] = (f32x4){0.f, 0.f, 0.f, 0.f};
        if (gid == 0) { starts[0] = 0; starts[NSEG] = T_TOK; }
        if (gid < T_TOK - 1) {
            int s0 = segids[gid], s1 = segids[gid + 1];
            if (s1 != s0) starts[s1] = gid + 1;
        }
    } else if (bid == 384) {
        // ---- prep ----
        __shared__ float cacc[4];
        if (t < 4)   cacc[t]   = 0.f;
        if (t < 128) segacc[t] = 0.f;
        __syncthreads();
        float s0 = 0.f, s1 = 0.f, s2 = 0.f, s3 = 0.f;
#pragma unroll
        for (int i = 0; i < 4; ++i) {
            int c = t + i * 256;
            float g = gamma[c], be = beta[c];
            float w0 = wout[2 * c], w1 = wout[2 * c + 1];
            float a0 = g * w0, a1 = g * w1;
            u0[c] = a0; u1[c] = a1;
            s0 += a0; s1 += a1; s2 += be * w0; s3 += be * w1;
        }
#pragma unroll
        for (int off = 32; off > 0; off >>= 1) {
            s0 += __shfl_down(s0, off, 64); s1 += __shfl_down(s1, off, 64);
            s2 += __shfl_down(s2, off, 64); s3 += __shfl_down(s3, off, 64);
        }
        if ((t & 63) == 0) {
            atomicAdd(&cacc[0], s0); atomicAdd(&cacc[1], s1);
            atomicAdd(&cacc[2], s2); atomicAdd(&cacc[3], s3);
        }
        __syncthreads();
        if (t < 4) consts[t] = cacc[t];
    } else {
        // ---- aconv: rb = bid-385; 128 rows x 1024 k -> 16 tiles of 16KB ----
        int rb = bid - 385;
        const float* src = A + (size_t)rb * 128 * HDIM;
        char* dstb = (char*)A16 + (size_t)rb * 16 * 16384;
        int lr = t >> 5;        // row within 8-row group
        int lc = t & 31;        // 16B chunk within 512B
        for (int r8 = 0; r8 < 128; r8 += 8) {
            int row = r8 + lr;
            const float* sp = src + (size_t)row * HDIM + lc * 4;
#pragma unroll
            for (int i = 0; i < 8; ++i) {
                f32x4 v = *(const f32x4*)(sp + i * 128);   // coalesced: 1KB/instr
                half4 h;
                h[0] = (_Float16)v[0]; h[1] = (_Float16)v[1];
                h[2] = (_Float16)v[2]; h[3] = (_Float16)v[3];
                int kbase = i * 128 + lc * 4;
                int kq = kbase >> 6, r6 = kbase & 63;
                int kh = r6 >> 3, jh = (r6 >> 2) & 1;
                *(half4*)(dstb + (size_t)kq * 16384 + (size_t)(kh * 128 + row) * 16 + jh * 8) = h;
            }
        }
    }
}

// ---------------------------------------------------------------------------
// gemm_fast: exact m97 structure. 128x128 tile, BK=64, 256 threads (4 waves
// 2x2, each wave 64x64 via 2x2 mfma_32x32x16_f16).  BOTH operands arrive via
// global_load_lds(16B) from pre-arranged fp16 tile images: linear LDS dest,
// conflict-free fragment ds_read_b128, zero VALU in staging.
// Epilogue: h = acc + b + r; per-row partial s1,s2,p0,p1 -> rowred atomics.
// ---------------------------------------------------------------------------
__global__ __launch_bounds__(256, 3) void gemm_fast(
    const _Float16* __restrict__ A16, const float* __restrict__ R,
    const float* __restrict__ bdense, const _Float16* __restrict__ Wt,
    const float* __restrict__ u0g, const float* __restrict__ u1g,
    float* __restrict__ rowred) {
    __shared__ __align__(16) char smem[32768];   // A:[0,16K) B:[16K,32K); epi reuses all
    int tid  = threadIdx.x;
    int lane = tid & 63, wave = tid >> 6;
    int ln = lane & 31, lh = lane >> 5;
    int wrow = wave >> 1, wcol = wave & 1;

    // XCD-local mapping: XCD x owns row panels == x (mod 8); its 8 col-sibling
    // blocks are consecutive -> A16 panel (256KB) L2-resident on that XCD.
    int bid  = blockIdx.x;
    int xcd  = bid & 7, seq = bid >> 3;
    int vcol = seq & 7;
    int vrow = (seq >> 3) * 8 + xcd;             // 0..511
    int rowBase = vrow * 128, colBase = vcol * 128;

    f32x16 acc[2][2];
#pragma unroll
    for (int tr = 0; tr < 2; ++tr)
#pragma unroll
        for (int tc = 0; tc < 2; ++tc)
#pragma unroll
            for (int i = 0; i < 16; ++i) acc[tr][tc][i] = 0.f;

    const char* asrc0 = (const char*)A16 + (size_t)(vrow * 16) * 16384 + wave * 4096 + lane * 16;
    const char* bsrc0 = (const char*)Wt  + (size_t)(vcol * 16) * 16384 + wave * 4096 + lane * 16;
    char* adst = smem + wave * 4096;             // wave-uniform dests
    char* bdst = smem + 16384 + wave * 4096;

    for (int kq = 0; kq < 16; ++kq) {
        __syncthreads();                         // previous tile fully consumed
        const char* as = asrc0 + (size_t)kq * 16384;
        const char* bs = bsrc0 + (size_t)kq * 16384;
#pragma unroll
        for (int i = 0; i < 4; ++i) {
            __builtin_amdgcn_global_load_lds((gvoid*)(as + i * 1024),
                                             (lvoid*)(adst + i * 1024), 16, 0, 0);
            __builtin_amdgcn_global_load_lds((gvoid*)(bs + i * 1024),
                                             (lvoid*)(bdst + i * 1024), 16, 0, 0);
        }
        __syncthreads();                         // vmcnt(0) drain: tile ready
#pragma unroll
        for (int ks = 0; ks < 4; ++ks) {
            int kh = ks * 2 + lh;
            half8 afr[2], bfr[2];
#pragma unroll
            for (int tr = 0; tr < 2; ++tr)
                afr[tr] = *(const half8*)(smem + (size_t)(kh * 128 + wrow * 64 + tr * 32 + ln) * 16);
#pragma unroll
            for (int tc = 0; tc < 2; ++tc)
                bfr[tc] = *(const half8*)(smem + 16384 + (size_t)(kh * 128 + wcol * 64 + tc * 32 + ln) * 16);
#pragma unroll
            for (int tr = 0; tr < 2; ++tr)
#pragma unroll
                for (int tc = 0; tc < 2; ++tc)
                    acc[tr][tc] = __builtin_amdgcn_mfma_f32_32x32x16_f16(
                        afr[tr], bfr[tc], acc[tr][tc], 0, 0, 0);
        }
    }

    // ---- epilogue ----
    __syncthreads();
    float* red = (float*)smem;                   // [4 q][128 rows][16 slots] = 32KB
#pragma unroll
    for (int i = 0; i < 32; ++i) red[tid + i * 256] = 0.f;
    __syncthreads();

    float bv[2], u0v[2], u1v[2];
#pragma unroll
    for (int tc = 0; tc < 2; ++tc) {
        int c = colBase + wcol * 64 + tc * 32 + ln;
        bv[tc] = bdense[c]; u0v[tc] = u0g[c]; u1v[tc] = u1g[c];
    }
    int slot = ln & 15;
#pragma unroll
    for (int tr = 0; tr < 2; ++tr)
#pragma unroll
        for (int reg = 0; reg < 16; ++reg) {
            int rIT  = (reg & 3) + 8 * (reg >> 2) + 4 * lh;   // C/D row map (m74/m101)
            int rloc = wrow * 64 + tr * 32 + rIT;
            size_t grow = (size_t)(rowBase + rloc);
            const float* rp = R + grow * HDIM + colBase + wcol * 64 + ln;
            float h0 = acc[tr][0][reg] + bv[0] + rp[0];
            float h1 = acc[tr][1][reg] + bv[1] + rp[32];
            atomicAdd(&red[(0 * 128 + rloc) * 16 + slot], h0 + h1);
            atomicAdd(&red[(1 * 128 + rloc) * 16 + slot], h0 * h0 + h1 * h1);
            atomicAdd(&red[(2 * 128 + rloc) * 16 + slot], h0 * u0v[0] + h1 * u0v[1]);
            atomicAdd(&red[(3 * 128 + rloc) * 16 + slot], h0 * u1v[0] + h1 * u1v[1]);
        }
    __syncthreads();
    for (int s = tid; s < 512; s += 256) {       // (q,row) pairs
        int q = s >> 7, row = s & 127;
        const float* rr = &red[(q * 128 + row) * 16];
        float v = 0.f;
#pragma unroll
        for (int c = 0; c < 16; ++c) v += rr[c];
        atomicAdd(&rowred[(size_t)(rowBase + row) * 4 + q], v);
    }
}

// ---------------------------------------------------------------------------
// gemm_fallback: round-1 kernel (reg-staged fp32 A) — used only if the
// workspace cannot hold the fp16 A image.
// ---------------------------------------------------------------------------
__global__ __launch_bounds__(256, 3) void gemm_fallback(
    const float* __restrict__ A, const float* __restrict__ R,
    const float* __restrict__ bdense, const _Float16* __restrict__ Wt,
    const float* __restrict__ u0g, const float* __restrict__ u1g,
    float* __restrict__ rowred) {
    __shared__ __align__(16) char smem[32768];
    int tid  = threadIdx.x;
    int lane = tid & 63, wave = tid >> 6;
    int ln = lane & 31, lh = lane >> 5;
    int wrow = wave >> 1, wcol = wave & 1;
    int bid  = blockIdx.x;
    int xcd  = bid & 7, seq = bid >> 3;
    int vcol = seq & 7;
    int vrow = (seq >> 3) * 8 + xcd;
    int rowBase = vrow * 128, colBase = vcol * 128;

    f32x16 acc[2][2];
#pragma unroll
    for (int tr = 0; tr < 2; ++tr)
#pragma unroll
        for (int tc = 0; tc < 2; ++tc)
#pragma unroll
            for (int i = 0; i < 16; ++i) acc[tr][tc][i] = 0.f;

    int srow = tid >> 1, shalf = tid & 1;
    const float* asrc0 = A + (size_t)(rowBase + srow) * HDIM + shalf * 32;
    char* aLds = smem;
    char* bLds = smem + 16384;
    char* aWr  = aLds + (size_t)(shalf * 4 * 128 + srow) * 16;
    const char* bsrc0 = (const char*)Wt + (size_t)(vcol * 16) * 16384 + wave * 4096 + lane * 16;
    char* bdst = bLds + wave * 4096;

    for (int kq = 0; kq < 16; ++kq) {
        __syncthreads();
        const char* bs = bsrc0 + (size_t)kq * 16384;
#pragma unroll
        for (int i = 0; i < 4; ++i)
            __builtin_amdgcn_global_load_lds((gvoid*)(bs + i * 1024),
                                             (lvoid*)(bdst + i * 1024), 16, 0, 0);
        const float* as = asrc0 + kq * 64;
        f32x4 a[8];
#pragma unroll
        for (int i = 0; i < 8; ++i) a[i] = *(const f32x4*)(as + i * 4);
#pragma unroll
        for (int j = 0; j < 4; ++j) {
            f32x4 lo = a[2 * j], hi = a[2 * j + 1];
            half8 s;
            s[0] = (_Float16)lo[0]; s[1] = (_Float16)lo[1];
            s[2] = (_Float16)lo[2]; s[3] = (_Float16)lo[3];
            s[4] = (_Float16)hi[0]; s[5] = (_Float16)hi[1];
            s[6] = (_Float16)hi[2]; s[7] = (_Float16)hi[3];
            *(half8*)(aWr + j * 2048) = s;
        }
        __syncthreads();
#pragma unroll
        for (int ks = 0; ks < 4; ++ks) {
            int kh = ks * 2 + lh;
            half8 afr[2], bfr[2];
#pragma unroll
            for (int tr = 0; tr < 2; ++tr)
                afr[tr] = *(const half8*)(aLds + (size_t)(kh * 128 + wrow * 64 + tr * 32 + ln) * 16);
#pragma unroll
            for (int tc = 0; tc < 2; ++tc)
                bfr[tc] = *(const half8*)(bLds + (size_t)(kh * 128 + wcol * 64 + tc * 32 + ln) * 16);
#pragma unroll
            for (int tr = 0; tr < 2; ++tr)
#pragma unroll
                for (int tc = 0; tc < 2; ++tc)
                    acc[tr][tc] = __builtin_amdgcn_mfma_f32_32x32x16_f16(
                        afr[tr], bfr[tc], acc[tr][tc], 0, 0, 0);
        }
    }

    __syncthreads();
    float* red = (float*)smem;
#pragma unroll
    for (int i = 0; i < 32; ++i) red[tid + i * 256] = 0.f;
    __syncthreads();

    float bv[2], u0v[2], u1v[2];
#pragma unroll
    for (int tc = 0; tc < 2; ++tc) {
        int c = colBase + wcol * 64 + tc * 32 + ln;
        bv[tc] = bdense[c]; u0v[tc] = u0g[c]; u1v[tc] = u1g[c];
    }
    int slot = ln & 15;
#pragma unroll
    for (int tr = 0; tr < 2; ++tr)
#pragma unroll
        for (int reg = 0; reg < 16; ++reg) {
            int rIT  = (reg & 3) + 8 * (reg >> 2) + 4 * lh;
            int rloc = wrow * 64 + tr * 32 + rIT;
            size_t grow = (size_t)(rowBase + rloc);
            const float* rp = R + grow * HDIM + colBase + wcol * 64 + ln;
            float h0 = acc[tr][0][reg] + bv[0] + rp[0];
            float h1 = acc[tr][1][reg] + bv[1] + rp[32];
            atomicAdd(&red[(0 * 128 + rloc) * 16 + slot], h0 + h1);
            atomicAdd(&red[(1 * 128 + rloc) * 16 + slot], h0 * h0 + h1 * h1);
            atomicAdd(&red[(2 * 128 + rloc) * 16 + slot], h0 * u0v[0] + h1 * u0v[1]);
            atomicAdd(&red[(3 * 128 + rloc) * 16 + slot], h0 * u1v[0] + h1 * u1v[1]);
        }
    __syncthreads();
    for (int s = tid; s < 512; s += 256) {
        int q = s >> 7, row = s & 127;
        const float* rr = &red[(q * 128 + row) * 16];
        float v = 0.f;
#pragma unroll
        for (int c = 0; c < 16; ++c) v += rr[c];
        atomicAdd(&rowred[(size_t)(rowBase + row) * 4 + q], v);
    }
}

// ---------------------------------------------------------------------------
// rowfinal: per-row LN finalize + segment-run combine.  256 blocks x 256.
// ---------------------------------------------------------------------------
__global__ void rowfinal_kernel(const float* __restrict__ rowred, const int* __restrict__ segids,
                                const float* __restrict__ consts, float* __restrict__ segacc) {
    __shared__ float sval[256][2];
    __shared__ int   sseg[256];
    int t   = threadIdx.x;
    int row = blockIdx.x * 256 + t;
    f32x4 v = ((const f32x4*)rowred)[row];       // s1,s2,p0,p1
    float mu  = v[0] * (1.f / 1024.f);
    float var = v[1] * (1.f / 1024.f) - mu * mu;
    float rsd = rsqrtf(var + 1e-12f);
    sval[t][0] = rsd * (v[2] - mu * consts[0]) + consts[2];
    sval[t][1] = rsd * (v[3] - mu * consts[1]) + consts[3];
    sseg[t] = segids[row];
    __syncthreads();
    int s = sseg[t];
    if (t == 255 || sseg[t + 1] != s) {          // run end -> one atomic pair per run
        float a0 = 0.f, a1 = 0.f;
        int rr = t;
        while (rr >= 0 && sseg[rr] == s) { a0 += sval[rr][0]; a1 += sval[rr][1]; --rr; }
        atomicAdd(&segacc[s * 2],     a0);
        atomicAdd(&segacc[s * 2 + 1], a1);
    }
}

// ---------------------------------------------------------------------------
// finalize: logits[b][l] = segacc[b][l] / count[b] + b_out[l]
// ---------------------------------------------------------------------------
__global__ void finalize_kernel(const float* __restrict__ segacc, const int* __restrict__ starts,
                                const float* __restrict__ bout, float* __restrict__ out) {
    int t = threadIdx.x;
    if (t < 128) {
        int s = t >> 1, l = t & 1;
        int cnt = starts[s + 1] - starts[s];
        out[t] = segacc[t] / (float)cnt + bout[l];
    }
}

extern "C" void kernel_launch(void* const* d_in, const int* in_sizes, int n_in,
                              void* d_out, int out_size, void* d_ws, size_t ws_size,
                              hipStream_t stream) {
    const float* A      = (const float*)d_in[0];  // sequence_attention_embeddings [T,H]
    const float* R      = (const float*)d_in[1];  // sequence_embeddings [T,H]
    const float* Wd     = (const float*)d_in[2];  // W_dense [H,H]
    const float* bdense = (const float*)d_in[3];  // b_dense [H]
    const float* gamma  = (const float*)d_in[4];  // gamma [H]
    const float* beta   = (const float*)d_in[5];  // beta [H]
    const float* wout   = (const float*)d_in[6];  // W_out [H,2]
    const float* bout   = (const float*)d_in[7];  // b_out [2]
    const int*   segids = (const int*)d_in[8];    // segment_ids [T]
    float* out = (float*)d_out;

    char* ws = (char*)d_ws;
    _Float16* Wt  = (_Float16*)(ws + WT_OFF);
    float* u0     = (float*)(ws + U0_OFF);
    float* u1     = (float*)(ws + U1_OFF);
    float* consts = (float*)(ws + CON_OFF);
    float* segacc = (float*)(ws + ACC_OFF);
    int*   starts = (int*)(ws + STARTS_OFF);
    float* rowred = (float*)(ws + ROWRED_OFF);
    _Float16* A16 = (_Float16*)(ws + A16_OFF);

    bool fast = (ws_size >= WS_NEED);

    setup_kernel<<<fast ? 897 : 385, 256, 0, stream>>>(
        A, Wd, gamma, beta, wout, segids, Wt, A16, u0, u1, consts, segacc, starts, rowred);
    if (fast)
        gemm_fast<<<4096, 256, 0, stream>>>(A16, R, bdense, Wt, u0, u1, rowred);
    else
        gemm_fallback<<<4096, 256, 0, stream>>>(A, R, bdense, Wt, u0, u1, rowred);
    rowfinal_kernel<<<256, 256, 0, stream>>>(rowred, segids, consts, segacc);
    finalize_kernel<<<1, 128, 0, stream>>>(segacc, starts, bout, out);
}